// Round 15
// baseline (191.922 us; speedup 1.0000x reference)
//
#include <hip/hip_runtime.h>
#include <math.h>

// B=32, Cin=64, H=W=56, Cout=128, K=3 pad=1 -> D=576, out (32,128,56,56) fp32
#define B_    32
#define CIN   64
#define HH    56
#define WW    56
#define COUT  128
#define DD    576
#define KC    384            // OpenBLAS kc split (verified R9)
#define LPX   (HH*WW)        // 3136 = 49*64
#define TOTAL (B_*COUT*LPX)
#define MARGIN 4e-4f         // worst-case split-bf16 + reorder bound (validated R15-18)

typedef __attribute__((ext_vector_type(8)))  short  short8;
typedef __attribute__((ext_vector_type(16))) float  float16v;

// bf16 RNE rounding kernel: BRNE(u) = u + 0x7FFF + lsb(u.hi); h = BRNE>>16.
// Identical arithmetic to the verified prep bf16_rne.
#define BRNE(u) ((u) + 0x7FFFu + (((u) >> 16) & 1u))

// ---- bit-exact numpy FLOAT_sin (npyv FMA path) — verified R9 ----
__device__ __forceinline__ float np_sinf(float x) {
#pragma clang fp contract(off)
    const float rint_cvt = 0x1.8p+23f;
    float q = __fmul_rn(x, 0x1.45f306p-1f);
    q = __fadd_rn(q, rint_cvt);
    q = __fsub_rn(q, rint_cvt);
    float r = fmaf(q, -0x1.921fb0p+0f, x);
    r = fmaf(q, -0x1.5110b4p-22f, r);
    r = fmaf(q, -0x1.846988p-48f, r);
    float r2 = __fmul_rn(r, r);
    float s = fmaf(0x1.7d3bbcp-19f, r2, -0x1.a06bbap-13f);
    s = fmaf(s, r2, 0x1.11119ap-7f);
    s = fmaf(s, r2, -0x1.555556p-3f);
    s = __fmul_rn(s, r2);
    s = fmaf(s, r, r);
    float c = fmaf(0x1.98e616p-16f, r2, -0x1.6c06dcp-10f);
    c = fmaf(c, r2, 0x1.55553cp-5f);
    c = fmaf(c, r2, -0.5f);
    c = fmaf(c, r2, 1.0f);
    int iq = (int)q;
    float res = (iq & 1) ? c : s;
    unsigned sgn = ((unsigned)(iq & 2)) << 30;
    return __uint_as_float(__float_as_uint(res) ^ sgn);
}
__device__ __forceinline__ int dec_np(float z) {
    float s = np_sinf(z);
    return (__fmul_rn(s, s) > 0.5f) ? 1 : 0;
}

// ---- SINGLE fused kernel (R15): conv + block-local fixup, NO prep stage.
// Ledger (R0-R14): each serialized dispatch stage costs ~30-58us regardless
// of its grid/layout; packed hi|lo words are the SAME 4B as raw fp32, so
// prep saved zero load bytes — its only function was hoisting split VALU.
// Now: gather raw fp32 (same addresses/coalescing; bounds via cndmask =
// R2-verified pattern) and split in-flow:
//   r0 = BRNE(u); h = r0>>16; lf = f - as_float(r0 & 0xFFFF0000);
//   r1 = BRNE(bits(lf));  pair-pack via v_perm(rb, ra, 0x07060302).
// Values bit-identical to prep's Wph/Wpl/xpad words -> MFMA inputs and the
// 6-MFMA/acc order identical to R5/R14 -> acc bit-identical -> MARGIN valid.
// Main loop structure = R14 (best measured); fixup phase = R14 (verified).
#define FRAG(t, s, hf, ln)  (((t) * 1024) + ((s) * 512) + ((hf) * 256) + ((ln) * 8))
#define SMEM_FIX  18432                  // sx[4][576] + sw[4][576] floats
#define SMEM_LIST 16384                  // ushort llist[8192]
__global__ __launch_bounds__(256, 4)
void conv_fused(const float* __restrict__ x,
                const float* __restrict__ Wt,
                const float* __restrict__ bias,
                float* __restrict__ out) {
    __shared__ __align__(16) char smem[SMEM_FIX + SMEM_LIST + 16];
    unsigned short* sP    = (unsigned short*)smem;        // conv: [hi|lo][2][2048]
    float*          sxB   = (float*)smem;                 // fixup overlay
    float*          swB   = sxB + 4 * DD;
    unsigned short* llist = (unsigned short*)(smem + SMEM_FIX);
    unsigned*       lcnt  = (unsigned*)(smem + SMEM_FIX + SMEM_LIST);

    const int tid = threadIdx.x;
    if (tid == 0) *lcnt = 0;             // published by first loop barrier
    // XCD-chunked bijective swizzle (1568 = 8*196): per-XCD contiguous chunk
    // = exactly 4 batches of x (~3.2MB) -> fits 4MB L2.
    const int bid = (blockIdx.x & 7) * 196 + (blockIdx.x >> 3);
    const int pt0 = bid * 64;            // 64-px tile, never crosses a batch

    const int plane = tid & 15;
    const int pair  = tid >> 4;
    const int s_st  = pair >> 3;
    const int h_st  = (pair >> 2) & 1;
    const int j2_st = pair & 3;

    const int bpos = pt0 / LPX;          // block-uniform batch
    const unsigned* xb = (const unsigned*)(x + (size_t)bpos * CIN * LPX);

    // per-r pixel coords + plane offset (bounds checked per element)
    int ypxA[4], xpxA[4];
    unsigned pbase[4];
#pragma unroll
    for (int r = 0; r < 4; ++r) {
        int gp = pt0 + plane + r * 16;
        int pr = gp - bpos * LPX;
        int ypx = pr / WW;
        int xpx = pr - ypx * WW;
        ypxA[r] = ypx;
        xpxA[r] = xpx;
        pbase[r] = (unsigned)(ypx * WW + xpx);
    }

    const int w    = tid >> 6;           // o-tile (0..3)
    const int lane = tid & 63;
    const int lm   = lane & 31;
    const int half = lane >> 5;
    // this lane's W row + k-phase: o = w*32+lm, k = it*32 + s*16 + half*8 + j
    const float* wrow = Wt + (size_t)(w * 32 + lm) * DD + half * 8;

    float16v acc[2];
#pragma unroll
    for (int n = 0; n < 2; ++n)
#pragma unroll
        for (int i = 0; i < 16; ++i) acc[n][i] = 0.f;

    unsigned pg[4][2], pgn[4][2];        // raw fp32 bits of patch elements
    float4 wA[4], wAn[4];                // raw W: [2*s + (0|1)] = 8 fp32 per s

#define LOADP(K0, DST)                                                         \
    {                                                                          \
        int d0 = (K0) + pair * 2;                                              \
        int c0 = d0 / 9, t0 = d0 - c0 * 9;                                     \
        int u0 = t0 / 3, v0 = t0 - u0 * 3;                                     \
        int t1 = t0 + 1, c1 = c0;                                              \
        if (t1 == 9) { t1 = 0; c1 = c0 + 1; }                                  \
        int u1 = t1 / 3, v1 = t1 - u1 * 3;                                     \
        int off0 = c0 * LPX + (u0 - 1) * WW + (v0 - 1);                        \
        int off1 = c1 * LPX + (u1 - 1) * WW + (v1 - 1);                        \
        _Pragma("unroll")                                                      \
        for (int r = 0; r < 4; ++r) {                                          \
            int gy0 = ypxA[r] + u0 - 1, gx0 = xpxA[r] + v0 - 1;                \
            int gy1 = ypxA[r] + u1 - 1, gx1 = xpxA[r] + v1 - 1;                \
            DST[r][0] = ((unsigned)gy0 < HH && (unsigned)gx0 < WW)             \
                            ? xb[pbase[r] + off0] : 0u;                        \
            DST[r][1] = ((unsigned)gy1 < HH && (unsigned)gx1 < WW)             \
                            ? xb[pbase[r] + off1] : 0u;                        \
        }                                                                      \
    }

#define LOADA(IT, DST)                                                         \
    _Pragma("unroll")                                                          \
    for (int s = 0; s < 2; ++s) {                                              \
        DST[2 * s]     = *(const float4*)(wrow + (IT) * 32 + s * 16);          \
        DST[2 * s + 1] = *(const float4*)(wrow + (IT) * 32 + s * 16 + 4);      \
    }

    // split 8 raw fp32 -> Ah[s] (4 words of h-pairs), Al[s] (l-pairs);
    // word m ushorts (2m,2m+1) ascending j — identical to prep_w's pack
#define SPLITA(SRC, AH, AL)                                                    \
    _Pragma("unroll")                                                          \
    for (int s = 0; s < 2; ++s) {                                              \
        unsigned fr0 = __float_as_uint(SRC[2 * s].x);                          \
        unsigned fr1 = __float_as_uint(SRC[2 * s].y);                          \
        unsigned fr2 = __float_as_uint(SRC[2 * s].z);                          \
        unsigned fr3 = __float_as_uint(SRC[2 * s].w);                          \
        unsigned fr4 = __float_as_uint(SRC[2 * s + 1].x);                      \
        unsigned fr5 = __float_as_uint(SRC[2 * s + 1].y);                      \
        unsigned fr6 = __float_as_uint(SRC[2 * s + 1].z);                      \
        unsigned fr7 = __float_as_uint(SRC[2 * s + 1].w);                      \
        unsigned fa[8] = {fr0, fr1, fr2, fr3, fr4, fr5, fr6, fr7};             \
        _Pragma("unroll")                                                      \
        for (int m = 0; m < 4; ++m) {                                          \
            unsigned ua = fa[2 * m], ub = fa[2 * m + 1];                       \
            unsigned r0a = BRNE(ua), r0b = BRNE(ub);                           \
            ((unsigned*)&AH[s])[m] =                                           \
                __builtin_amdgcn_perm(r0b, r0a, 0x07060302u);                  \
            float lfa = __uint_as_float(ua) -                                  \
                        __uint_as_float(r0a & 0xFFFF0000u);                    \
            float lfb = __uint_as_float(ub) -                                  \
                        __uint_as_float(r0b & 0xFFFF0000u);                    \
            unsigned r1a = BRNE(__float_as_uint(lfa));                         \
            unsigned r1b = BRNE(__float_as_uint(lfb));                         \
            ((unsigned*)&AL[s])[m] =                                           \
                __builtin_amdgcn_perm(r1b, r1a, 0x07060302u);                  \
        }                                                                      \
    }

    LOADP(0, pg)
    LOADA(0, wA)

#pragma unroll
    for (int it = 0; it < 18; ++it) {
        unsigned short* bPh = sP + (it & 1) * 2048;
        unsigned short* bPl = sP + 4096 + (it & 1) * 2048;

        // publish step it's patches: in-flow split (bit-identical to prep's
        // hw/lw words: hw = h0|h1<<16, lw = l0|l1<<16)
#pragma unroll
        for (int r = 0; r < 4; ++r) {
            unsigned ua = pg[r][0], ub = pg[r][1];
            unsigned r0a = BRNE(ua), r0b = BRNE(ub);
            float lfa = __uint_as_float(ua) - __uint_as_float(r0a & 0xFFFF0000u);
            float lfb = __uint_as_float(ub) - __uint_as_float(r0b & 0xFFFF0000u);
            unsigned r1a = BRNE(__float_as_uint(lfa));
            unsigned r1b = BRNE(__float_as_uint(lfb));
            unsigned hw = __builtin_amdgcn_perm(r0b, r0a, 0x07060302u);
            unsigned lw = __builtin_amdgcn_perm(r1b, r1a, 0x07060302u);
            int pm = plane + (r & 1) * 16;
            int word = (r >> 1) * 512 + s_st * 256 + h_st * 128 + pm * 4 + j2_st;
            ((unsigned*)bPh)[word] = hw;
            ((unsigned*)bPl)[word] = lw;
        }

        // issue next step's A + P raw loads; they land under the MFMA phase
        if (it < 17) {
            LOADA(it + 1, wAn)
            LOADP((it + 1) * 32, pgn)
        }

        // drain own ds ops, rendezvous; prefetch loads stay in flight
        asm volatile("s_waitcnt lgkmcnt(0)" ::: "memory");
        __builtin_amdgcn_s_barrier();
        asm volatile("" ::: "memory");

        // split current A (overlaps with B-fragment ds_reads)
        uint4 Ah[2], Al[2];
        SPLITA(wA, Ah, Al)

#pragma unroll
        for (int n = 0; n < 2; ++n) {
            short8 Bh0 = *(const short8*)(bPh + FRAG(n, 0, half, lm));
            short8 Bl0 = *(const short8*)(bPl + FRAG(n, 0, half, lm));
            short8 Bh1 = *(const short8*)(bPh + FRAG(n, 1, half, lm));
            short8 Bl1 = *(const short8*)(bPl + FRAG(n, 1, half, lm));
            acc[n] = __builtin_amdgcn_mfma_f32_32x32x16_bf16(
                *(const short8*)&Ah[0], Bh0, acc[n], 0, 0, 0);
            acc[n] = __builtin_amdgcn_mfma_f32_32x32x16_bf16(
                *(const short8*)&Ah[0], Bl0, acc[n], 0, 0, 0);
            acc[n] = __builtin_amdgcn_mfma_f32_32x32x16_bf16(
                *(const short8*)&Al[0], Bh0, acc[n], 0, 0, 0);
            acc[n] = __builtin_amdgcn_mfma_f32_32x32x16_bf16(
                *(const short8*)&Ah[1], Bh1, acc[n], 0, 0, 0);
            acc[n] = __builtin_amdgcn_mfma_f32_32x32x16_bf16(
                *(const short8*)&Ah[1], Bl1, acc[n], 0, 0, 0);
            acc[n] = __builtin_amdgcn_mfma_f32_32x32x16_bf16(
                *(const short8*)&Al[1], Bh1, acc[n], 0, 0, 0);
        }

        if (it < 17) {
#pragma unroll
            for (int r = 0; r < 4; ++r) {
                pg[r][0] = pgn[r][0];
                pg[r][1] = pgn[r][1];
            }
#pragma unroll
            for (int s = 0; s < 4; ++s) wA[s] = wAn[s];
        }
    }
#undef LOADP
#undef LOADA
#undef SPLITA

    // epilogue: provisional STE bit; record margin hits to block-local list
#pragma unroll
    for (int n = 0; n < 2; ++n) {
        const int gp0 = pt0 + n * 32;
        const int pxb = gp0 - bpos * LPX + lm;
        const size_t outb = (size_t)bpos * COUT * LPX;
#pragma unroll
        for (int reg = 0; reg < 16; ++reg) {
            int o = w * 32 + 4 * half + (reg & 3) + 8 * (reg >> 2);
            float z = acc[n][reg] + bias[o];
            float q = rintf(__fmul_rn(z, 0.63661975f));
            float rr = fmaf(q, -1.5707964f, z);
            float d = fabsf(fabsf(rr) - 0.78539816f);
            size_t oidx = outb + (size_t)o * LPX + pxb;
            out[oidx] = (float)(((int)q) & 1);
            if (d < MARGIN) {
                unsigned p = atomicAdd(lcnt, 1u);
                llist[p] = (unsigned short)(tid * 32 + n * 16 + reg);
            }
        }
    }

    // ---- block-local wave-cooperative fixup phase (verified R14) ----
    __syncthreads();                     // all hits recorded; sP dead
    const unsigned cnt = *lcnt;          // block-uniform
    const int wv = w;                    // wave id 0..3
    for (unsigned base = 0; base < cnt; base += 4) {
        __syncthreads();                 // sx/sw free (prev chunk consumed)
        unsigned ei = base + wv;
        int o_e = 0;
        size_t idx_e = 0;
        if (ei < cnt) {
            unsigned e = llist[ei];
            int tid_e = e >> 5;
            int n_e   = (e >> 4) & 1;
            int reg_e = e & 15;
            o_e = ((tid_e >> 6) << 5) + 4 * ((tid_e & 63) >> 5)
                  + (reg_e & 3) + 8 * (reg_e >> 2);
            int gp = pt0 + n_e * 32 + (tid_e & 31);
            int b_e = gp / LPX;
            int pix = gp - b_e * LPX;
            int py_e = pix / WW;
            int px_e = pix - py_e * WW;
            idx_e = (size_t)b_e * COUT * LPX + (size_t)o_e * LPX + pix;
            // gather: lane = channel c (byte-identical sx/sw to R14/R9 path)
            const float* xc = x  + ((size_t)(b_e * CIN + lane)) * LPX;
            const float* wc = Wt + (size_t)o_e * DD + lane * 9;
#pragma unroll
            for (int u = 0; u < 3; ++u)
#pragma unroll
                for (int v = 0; v < 3; ++v) {
                    int tp = u * 3 + v;
                    int gy = py_e + u - 1, gx = px_e + v - 1;
                    float p = ((unsigned)gy < HH && (unsigned)gx < WW)
                                  ? xc[gy * WW + gx] : 0.f;
                    sxB[wv * DD + lane * 9 + tp] = p;
                    swB[wv * DD + lane * 9 + tp] = wc[tp];
                }
        }
        __syncthreads();
        if (ei < cnt && lane == 0) {
#pragma clang fp contract(off)
            const float* px_ = sxB + wv * DD;
            const float* pw_ = swB + wv * DD;
            float accA = 0.f, accB2 = 0.f;
            for (int d = 0; d < KC; ++d)        accA  = fmaf(px_[d], pw_[d], accA);
            for (int d = KC; d < DD; ++d)       accB2 = fmaf(px_[d], pw_[d], accB2);
            float zG = __fadd_rn(accA, accB2);
            float z  = __fadd_rn(zG, bias[o_e]);
            out[idx_e] = (float)dec_np(z);
        }
    }
}

extern "C" void kernel_launch(void* const* d_in, const int* in_sizes, int n_in,
                              void* d_out, int out_size, void* d_ws, size_t ws_size,
                              hipStream_t stream) {
    const float* x  = (const float*)d_in[0];
    const float* Wt = (const float*)d_in[1];
    const float* bb = (const float*)d_in[2];
    float* out = (float*)d_out;

    // single fused launch: no prep stage, no workspace, no serialized tail
    conv_fused<<<dim3(1568), dim3(256), 0, stream>>>(x, Wt, bb, out);
}

// Round 16
// 185.321 us; speedup vs baseline: 1.0356x; 1.0356x over previous
//
#include <hip/hip_runtime.h>
#include <math.h>

// B=32, Cin=64, H=W=56, Cout=128, K=3 pad=1 -> D=576, out (32,128,56,56) fp32
#define B_    32
#define CIN   64
#define HH    56
#define WW    56
#define COUT  128
#define DD    576
#define KC    384            // OpenBLAS kc split (verified R9)
#define LPX   (HH*WW)        // 3136 = 49*64
#define TOTAL (B_*COUT*LPX)
#define NX    (B_*CIN*LPX)   // 6422528
#define PW    58             // padded plane width/height
#define PPL   (PW*PW)        // 3364 words per padded channel plane
#define NXP   (B_*CIN*PPL)   // 6889472 words
#define MARGIN 4e-4f         // worst-case split-bf16 + reorder bound (validated R15-18)

typedef __attribute__((ext_vector_type(8)))  short  short8;
typedef __attribute__((ext_vector_type(16))) float  float16v;

__device__ __forceinline__ unsigned short bf16_rne(float f) {
    unsigned u = __float_as_uint(f);
    unsigned r = u + 0x7FFFu + ((u >> 16) & 1u);
    return (unsigned short)(r >> 16);
}
__device__ __forceinline__ float bf16_to_f(unsigned short h) {
    return __uint_as_float(((unsigned)h) << 16);
}

// ---- bit-exact numpy FLOAT_sin (npyv FMA path) — verified R9 ----
__device__ __forceinline__ float np_sinf(float x) {
#pragma clang fp contract(off)
    const float rint_cvt = 0x1.8p+23f;
    float q = __fmul_rn(x, 0x1.45f306p-1f);
    q = __fadd_rn(q, rint_cvt);
    q = __fsub_rn(q, rint_cvt);
    float r = fmaf(q, -0x1.921fb0p+0f, x);
    r = fmaf(q, -0x1.5110b4p-22f, r);
    r = fmaf(q, -0x1.846988p-48f, r);
    float r2 = __fmul_rn(r, r);
    float s = fmaf(0x1.7d3bbcp-19f, r2, -0x1.a06bbap-13f);
    s = fmaf(s, r2, 0x1.11119ap-7f);
    s = fmaf(s, r2, -0x1.555556p-3f);
    s = __fmul_rn(s, r2);
    s = fmaf(s, r, r);
    float c = fmaf(0x1.98e616p-16f, r2, -0x1.6c06dcp-10f);
    c = fmaf(c, r2, 0x1.55553cp-5f);
    c = fmaf(c, r2, -0.5f);
    c = fmaf(c, r2, 1.0f);
    int iq = (int)q;
    float res = (iq & 1) ? c : s;
    unsigned sgn = ((unsigned)(iq & 2)) << 30;
    return __uint_as_float(__float_as_uint(res) ^ sgn);
}
__device__ __forceinline__ int dec_np(float z) {
    float s = np_sinf(z);
    return (__fmul_rn(s, s) > 0.5f) ? 1 : 0;
}

// ---- merged prep (x4 vectorized, verified R9/R12/R14): W -> fragment-major
// bf16 hi/lo pack, x -> padded 58x58 planes of (hi | lo<<16) u32 words ----
// (R15 lesson: in-flow splitting costs more conv VALU than the prep stage
// costs wall — the A-split redundancy across 1568 blocks dominates. Keep prep.)
__global__ __launch_bounds__(256)
void prep_all(const float* __restrict__ x, const float* __restrict__ W,
              unsigned* __restrict__ xpad,
              unsigned short* __restrict__ Wph, unsigned short* __restrict__ Wpl) {
    int i4 = (blockIdx.x * 256 + threadIdx.x) * 4;
    if (i4 < COUT * DD) {               // COUT*DD % 4 == 0
#pragma unroll
        for (int e = 0; e < 4; ++e) {
            int i = i4 + e;
            int o = i / DD, k = i - o * DD;
            float w = W[i];
            unsigned short h = bf16_rne(w);
            unsigned short l = bf16_rne(w - bf16_to_f(h));
            int k18 = k >> 5, kr = k & 31;
            int s = (kr >> 4) & 1, half = (kr >> 3) & 1, j = kr & 7;
            int lane = half * 32 + (o & 31);
            int ot = o >> 5;
            unsigned dst = ((((unsigned)(k18 * 4 + ot)) * 2 + s) * 64 + lane) * 8 + j;
            Wph[dst] = h;
            Wpl[dst] = l;
        }
    }
    if (i4 < NXP) {                      // NXP % 4 == 0
        unsigned vv[4];
#pragma unroll
        for (int e = 0; e < 4; ++e) {
            int i = i4 + e;
            int bc = i / PPL;
            int r  = i - bc * PPL;
            int yy = r / PW;
            int xx = r - yy * PW;
            unsigned v = 0u;
            if (yy >= 1 && yy <= HH && xx >= 1 && xx <= WW) {
                float f = x[(size_t)bc * LPX + (yy - 1) * WW + (xx - 1)];
                unsigned short h = bf16_rne(f);
                unsigned short l = bf16_rne(f - bf16_to_f(h));
                v = (unsigned)h | ((unsigned)l << 16);
            }
            vv[e] = v;
        }
        *(uint4*)(xpad + i4) = *(uint4*)vv;
    }
}

// ---- MFMA conv with BLOCK-LOCAL fixup phase = EXACT R14 (verified 169.1us
// total, absmax 0), with two deltas:
//  (1) SMEM_LIST 16KB -> 4KB (2048 entries = ~490x the measured ~4.2
//      hits/block mean; cnt clamped defensively) -> LDS 34.8 -> 22.5 KB.
//  (2) __launch_bounds__(256, 5): reg cap 102 > ~92 needed (R10's failure
//      was bound 6 -> cap 85 -> spill; bound 5 fits) -> 5 blocks/CU, +25% TLP.
#define FRAG(t, s, hf, ln)  (((t) * 1024) + ((s) * 512) + ((hf) * 256) + ((ln) * 8))
#define SMEM_FIX  18432                  // sx[4][576] + sw[4][576] floats
#define LIST_CAP  2048u
#define SMEM_LIST 4096                   // ushort llist[2048]
__global__ __launch_bounds__(256, 5)
void conv_mfma(const unsigned* __restrict__ xpad,
               const unsigned short* __restrict__ Wph,
               const unsigned short* __restrict__ Wpl,
               const float* __restrict__ bias,
               float* __restrict__ out,
               const float* __restrict__ x,
               const float* __restrict__ Wt) {
    __shared__ __align__(16) char smem[SMEM_FIX + SMEM_LIST + 16];
    unsigned short* sP    = (unsigned short*)smem;        // conv: [hi|lo][2][2048]
    float*          sxB   = (float*)smem;                 // fixup overlay
    float*          swB   = sxB + 4 * DD;
    unsigned short* llist = (unsigned short*)(smem + SMEM_FIX);
    unsigned*       lcnt  = (unsigned*)(smem + SMEM_FIX + SMEM_LIST);

    const int tid = threadIdx.x;
    if (tid == 0) *lcnt = 0;             // published by first loop barrier
    // XCD-chunked bijective swizzle (1568 = 8*196): per-XCD contiguous chunk
    // = exactly 4 batches of xpad (~3.4MB -> fits 4MB L2).
    const int bid = (blockIdx.x & 7) * 196 + (blockIdx.x >> 3);
    const int pt0 = bid * 64;            // 64-px tile, never crosses a batch

    const int plane = tid & 15;
    const int pair  = tid >> 4;
    const int s_st  = pair >> 3;
    const int h_st  = (pair >> 2) & 1;
    const int j2_st = pair & 3;

    // per-r pixel bases into padded x (b folded in; LPX%64==0 so b-uniform)
    unsigned pbase[4];
#pragma unroll
    for (int r = 0; r < 4; ++r) {
        int gp = pt0 + plane + r * 16;
        int br = gp / LPX;
        int pr = gp - br * LPX;
        int ypx = pr / WW;
        int xpx = pr - ypx * WW;
        pbase[r] = (unsigned)(br * (CIN * PPL) + ypx * PW + xpx);
    }

    const int w    = tid >> 6;           // o-tile (0..3)
    const int lane = tid & 63;
    const int lm   = lane & 31;
    const int half = lane >> 5;
    const uint4* wAh = (const uint4*)Wph + w * 128 + lane;
    const uint4* wAl = (const uint4*)Wpl + w * 128 + lane;

    float16v acc[2];
#pragma unroll
    for (int n = 0; n < 2; ++n)
#pragma unroll
        for (int i = 0; i < 16; ++i) acc[n][i] = 0.f;

    unsigned pg[4][2], pgn[4][2];
    uint4 Ah[2], Al[2], Ahn[2], Aln[2];

#define LOADP(K0, DST)                                                         \
    {                                                                          \
        int d0 = (K0) + pair * 2;                                              \
        int c0 = d0 / 9, t0 = d0 - c0 * 9;                                     \
        int u0 = t0 / 3, v0 = t0 - u0 * 3;                                     \
        int t1 = t0 + 1, c1 = c0;                                              \
        if (t1 == 9) { t1 = 0; c1 = c0 + 1; }                                  \
        int u1 = t1 / 3, v1 = t1 - u1 * 3;                                     \
        unsigned off0 = (unsigned)(c0 * PPL + u0 * PW + v0);                   \
        unsigned off1 = (unsigned)(c1 * PPL + u1 * PW + v1);                   \
        _Pragma("unroll")                                                      \
        for (int r = 0; r < 4; ++r) {                                          \
            DST[r][0] = xpad[pbase[r] + off0];                                 \
            DST[r][1] = xpad[pbase[r] + off1];                                 \
        }                                                                      \
    }

#define LOADA(IT, DH, DL)                                                      \
    _Pragma("unroll")                                                          \
    for (int s = 0; s < 2; ++s) {                                              \
        DH[s] = wAh[(IT) * 512 + s * 64];                                      \
        DL[s] = wAl[(IT) * 512 + s * 64];                                      \
    }

    LOADP(0, pg)
    LOADA(0, Ah, Al)

#pragma unroll
    for (int it = 0; it < 18; ++it) {
        unsigned short* bPh = sP + (it & 1) * 2048;
        unsigned short* bPl = sP + 4096 + (it & 1) * 2048;

        // publish step it's patches (prefetched regs -> LDS)
#pragma unroll
        for (int r = 0; r < 4; ++r) {
            unsigned g0 = pg[r][0], g1 = pg[r][1];
            unsigned hw = (g0 & 0xFFFFu) | (g1 << 16);
            unsigned lw = (g0 >> 16) | (g1 & 0xFFFF0000u);
            int pm = plane + (r & 1) * 16;
            int word = (r >> 1) * 512 + s_st * 256 + h_st * 128 + pm * 4 + j2_st;
            ((unsigned*)bPh)[word] = hw;
            ((unsigned*)bPl)[word] = lw;
        }

        // issue next step's A + P loads; they land under the MFMA phase
        if (it < 17) {
            LOADA(it + 1, Ahn, Aln)
            LOADP((it + 1) * 32, pgn)
        }

        // drain own ds ops, rendezvous; prefetch loads stay in flight
        asm volatile("s_waitcnt lgkmcnt(0)" ::: "memory");
        __builtin_amdgcn_s_barrier();
        asm volatile("" ::: "memory");

#pragma unroll
        for (int n = 0; n < 2; ++n) {
            short8 Bh0 = *(const short8*)(bPh + FRAG(n, 0, half, lm));
            short8 Bl0 = *(const short8*)(bPl + FRAG(n, 0, half, lm));
            short8 Bh1 = *(const short8*)(bPh + FRAG(n, 1, half, lm));
            short8 Bl1 = *(const short8*)(bPl + FRAG(n, 1, half, lm));
            acc[n] = __builtin_amdgcn_mfma_f32_32x32x16_bf16(
                *(const short8*)&Ah[0], Bh0, acc[n], 0, 0, 0);
            acc[n] = __builtin_amdgcn_mfma_f32_32x32x16_bf16(
                *(const short8*)&Ah[0], Bl0, acc[n], 0, 0, 0);
            acc[n] = __builtin_amdgcn_mfma_f32_32x32x16_bf16(
                *(const short8*)&Al[0], Bh0, acc[n], 0, 0, 0);
            acc[n] = __builtin_amdgcn_mfma_f32_32x32x16_bf16(
                *(const short8*)&Ah[1], Bh1, acc[n], 0, 0, 0);
            acc[n] = __builtin_amdgcn_mfma_f32_32x32x16_bf16(
                *(const short8*)&Ah[1], Bl1, acc[n], 0, 0, 0);
            acc[n] = __builtin_amdgcn_mfma_f32_32x32x16_bf16(
                *(const short8*)&Al[1], Bh1, acc[n], 0, 0, 0);
        }

        if (it < 17) {
#pragma unroll
            for (int r = 0; r < 4; ++r) {
                pg[r][0] = pgn[r][0];
                pg[r][1] = pgn[r][1];
            }
#pragma unroll
            for (int s = 0; s < 2; ++s) {
                Ah[s] = Ahn[s];
                Al[s] = Aln[s];
            }
        }
    }
#undef LOADP
#undef LOADA

    // epilogue: provisional STE bit; record margin hits to block-local list
#pragma unroll
    for (int n = 0; n < 2; ++n) {
        const int gp0 = pt0 + n * 32;
        const int bpos = gp0 / LPX;
        const int pxb = gp0 - bpos * LPX + lm;
        const size_t outb = (size_t)bpos * COUT * LPX;
#pragma unroll
        for (int reg = 0; reg < 16; ++reg) {
            int o = w * 32 + 4 * half + (reg & 3) + 8 * (reg >> 2);
            float z = acc[n][reg] + bias[o];
            float q = rintf(__fmul_rn(z, 0.63661975f));
            float rr = fmaf(q, -1.5707964f, z);
            float d = fabsf(fabsf(rr) - 0.78539816f);
            size_t oidx = outb + (size_t)o * LPX + pxb;
            out[oidx] = (float)(((int)q) & 1);
            if (d < MARGIN) {
                unsigned p = atomicAdd(lcnt, 1u);
                if (p < LIST_CAP)
                    llist[p] = (unsigned short)(tid * 32 + n * 16 + reg);
            }
        }
    }

    // ---- block-local wave-cooperative fixup phase (verified R14) ----
    __syncthreads();                     // all hits recorded; sP dead
    unsigned cnt = *lcnt;                // block-uniform
    if (cnt > LIST_CAP) cnt = LIST_CAP;
    const int wv = w;                    // wave id 0..3
    for (unsigned base = 0; base < cnt; base += 4) {
        __syncthreads();                 // sx/sw free (prev chunk consumed)
        unsigned ei = base + wv;
        int o_e = 0;
        size_t idx_e = 0;
        if (ei < cnt) {
            unsigned e = llist[ei];
            int tid_e = e >> 5;
            int n_e   = (e >> 4) & 1;
            int reg_e = e & 15;
            o_e = ((tid_e >> 6) << 5) + 4 * ((tid_e & 63) >> 5)
                  + (reg_e & 3) + 8 * (reg_e >> 2);
            int gp = pt0 + n_e * 32 + (tid_e & 31);
            int b_e = gp / LPX;
            int pix = gp - b_e * LPX;
            int py_e = pix / WW;
            int px_e = pix - py_e * WW;
            idx_e = (size_t)b_e * COUT * LPX + (size_t)o_e * LPX + pix;
            // gather: lane = channel c (byte-identical sx/sw to R14/R9 path)
            const float* xc = x  + ((size_t)(b_e * CIN + lane)) * LPX;
            const float* wc = Wt + (size_t)o_e * DD + lane * 9;
#pragma unroll
            for (int u = 0; u < 3; ++u)
#pragma unroll
                for (int v = 0; v < 3; ++v) {
                    int tp = u * 3 + v;
                    int gy = py_e + u - 1, gx = px_e + v - 1;
                    float p = ((unsigned)gy < HH && (unsigned)gx < WW)
                                  ? xc[gy * WW + gx] : 0.f;
                    sxB[wv * DD + lane * 9 + tp] = p;
                    swB[wv * DD + lane * 9 + tp] = wc[tp];
                }
        }
        __syncthreads();
        if (ei < cnt && lane == 0) {
#pragma clang fp contract(off)
            const float* px_ = sxB + wv * DD;
            const float* pw_ = swB + wv * DD;
            float accA = 0.f, accB2 = 0.f;
            for (int d = 0; d < KC; ++d)        accA  = fmaf(px_[d], pw_[d], accA);
            for (int d = KC; d < DD; ++d)       accB2 = fmaf(px_[d], pw_[d], accB2);
            float zG = __fadd_rn(accA, accB2);
            float z  = __fadd_rn(zG, bias[o_e]);
            out[idx_e] = (float)dec_np(z);
        }
    }
}

// ---- fallback (verified R9 path) ----
__global__ __launch_bounds__(256)
void np_emul_conv(const float* __restrict__ x,
                  const float* __restrict__ Wt,
                  const float* __restrict__ bias,
                  float* __restrict__ out) {
#pragma clang fp contract(off)
    int idx = blockIdx.x * 256 + threadIdx.x;
    if (idx >= TOTAL) return;
    int px = idx % WW;
    int t  = idx / WW;
    int py = t % HH;  t /= HH;
    int o  = t % COUT;
    int b  = t / COUT;
    const float* wrow = Wt + (size_t)o * DD;
    const float* xb   = x + (size_t)b * CIN * LPX;
    float accA = 0.f, accB2 = 0.f;
    for (int c = 0; c < CIN; ++c) {
        const float* xc = xb + c * LPX;
        const float* wc = wrow + c * 9;
        int dbase = c * 9;
#pragma unroll
        for (int u = 0; u < 3; ++u)
#pragma unroll
            for (int v = 0; v < 3; ++v) {
                int tp = u * 3 + v;
                int gy = py + u - 1, gx = px + v - 1;
                float p = ((unsigned)gy < HH && (unsigned)gx < WW) ? xc[gy * WW + gx] : 0.f;
                if (dbase + tp < KC) accA  = fmaf(p, wc[tp], accA);
                else                 accB2 = fmaf(p, wc[tp], accB2);
            }
    }
    float z = __fadd_rn(__fadd_rn(accA, accB2), bias[o]);
    out[idx] = (float)dec_np(z);
}

extern "C" void kernel_launch(void* const* d_in, const int* in_sizes, int n_in,
                              void* d_out, int out_size, void* d_ws, size_t ws_size,
                              hipStream_t stream) {
    const float* x  = (const float*)d_in[0];
    const float* Wt = (const float*)d_in[1];
    const float* bb = (const float*)d_in[2];
    float* out = (float*)d_out;

    const size_t WSPLIT = (size_t)COUT * DD * 2;          // 147456 B each
    const size_t XP     = (size_t)NXP * 4;                // 27.56 MB padded
    const size_t FIXED  = 2 * WSPLIT + XP;

    if (ws_size >= FIXED + 4096) {
        unsigned short* Wph = (unsigned short*)d_ws;
        unsigned short* Wpl = Wph + COUT * DD;
        unsigned* xpad = (unsigned*)((char*)d_ws + 2 * WSPLIT);

        prep_all<<<dim3(NXP / 4 / 256), dim3(256), 0, stream>>>(x, Wt, xpad, Wph, Wpl);
        conv_mfma<<<dim3(1568), dim3(256), 0, stream>>>(xpad, Wph, Wpl, bb, out, x, Wt);
    } else {
        np_emul_conv<<<(TOTAL + 255) / 256, 256, 0, stream>>>(x, Wt, bb, out);
    }
}

// Round 18
// 167.204 us; speedup vs baseline: 1.1478x; 1.1084x over previous
//
#include <hip/hip_runtime.h>
#include <math.h>

// B=32, Cin=64, H=W=56, Cout=128, K=3 pad=1 -> D=576, out (32,128,56,56) fp32
#define B_    32
#define CIN   64
#define HH    56
#define WW    56
#define COUT  128
#define DD    576
#define KC    384            // OpenBLAS kc split (verified R9)
#define LPX   (HH*WW)        // 3136 = 49*64
#define TOTAL (B_*COUT*LPX)
#define NX    (B_*CIN*LPX)   // 6422528
#define PW    58             // padded plane width/height
#define PPL   (PW*PW)        // 3364 words per padded channel plane
#define NXP   (B_*CIN*PPL)   // 6889472 words
#define MARGIN 4e-4f         // worst-case split-bf16 + reorder bound (validated R15-18)

typedef __attribute__((ext_vector_type(8)))  short  short8;
typedef __attribute__((ext_vector_type(16))) float  float16v;

__device__ __forceinline__ unsigned short bf16_rne(float f) {
    unsigned u = __float_as_uint(f);
    unsigned r = u + 0x7FFFu + ((u >> 16) & 1u);
    return (unsigned short)(r >> 16);
}
__device__ __forceinline__ float bf16_to_f(unsigned short h) {
    return __uint_as_float(((unsigned)h) << 16);
}

// ---- bit-exact numpy FLOAT_sin (npyv FMA path) — verified R9 ----
__device__ __forceinline__ float np_sinf(float x) {
#pragma clang fp contract(off)
    const float rint_cvt = 0x1.8p+23f;
    float q = __fmul_rn(x, 0x1.45f306p-1f);
    q = __fadd_rn(q, rint_cvt);
    q = __fsub_rn(q, rint_cvt);
    float r = fmaf(q, -0x1.921fb0p+0f, x);
    r = fmaf(q, -0x1.5110b4p-22f, r);
    r = fmaf(q, -0x1.846988p-48f, r);
    float r2 = __fmul_rn(r, r);
    float s = fmaf(0x1.7d3bbcp-19f, r2, -0x1.a06bbap-13f);
    s = fmaf(s, r2, 0x1.11119ap-7f);
    s = fmaf(s, r2, -0x1.555556p-3f);
    s = __fmul_rn(s, r2);
    s = fmaf(s, r, r);
    float c = fmaf(0x1.98e616p-16f, r2, -0x1.6c06dcp-10f);
    c = fmaf(c, r2, 0x1.55553cp-5f);
    c = fmaf(c, r2, -0.5f);
    c = fmaf(c, r2, 1.0f);
    int iq = (int)q;
    float res = (iq & 1) ? c : s;
    unsigned sgn = ((unsigned)(iq & 2)) << 30;
    return __uint_as_float(__float_as_uint(res) ^ sgn);
}
__device__ __forceinline__ int dec_np(float z) {
    float s = np_sinf(z);
    return (__fmul_rn(s, s) > 0.5f) ? 1 : 0;
}

// ---- merged prep (x4 vectorized, verified R9/R12/R14): W -> fragment-major
// bf16 hi/lo pack, x -> padded 58x58 planes of (hi | lo<<16) u32 words ----
__global__ __launch_bounds__(256)
void prep_all(const float* __restrict__ x, const float* __restrict__ W,
              unsigned* __restrict__ xpad,
              unsigned short* __restrict__ Wph, unsigned short* __restrict__ Wpl) {
    int i4 = (blockIdx.x * 256 + threadIdx.x) * 4;
    if (i4 < COUT * DD) {               // COUT*DD % 4 == 0
#pragma unroll
        for (int e = 0; e < 4; ++e) {
            int i = i4 + e;
            int o = i / DD, k = i - o * DD;
            float w = W[i];
            unsigned short h = bf16_rne(w);
            unsigned short l = bf16_rne(w - bf16_to_f(h));
            int k18 = k >> 5, kr = k & 31;
            int s = (kr >> 4) & 1, half = (kr >> 3) & 1, j = kr & 7;
            int lane = half * 32 + (o & 31);
            int ot = o >> 5;
            unsigned dst = ((((unsigned)(k18 * 4 + ot)) * 2 + s) * 64 + lane) * 8 + j;
            Wph[dst] = h;
            Wpl[dst] = l;
        }
    }
    if (i4 < NXP) {                      // NXP % 4 == 0
        unsigned vv[4];
#pragma unroll
        for (int e = 0; e < 4; ++e) {
            int i = i4 + e;
            int bc = i / PPL;
            int r  = i - bc * PPL;
            int yy = r / PW;
            int xx = r - yy * PW;
            unsigned v = 0u;
            if (yy >= 1 && yy <= HH && xx >= 1 && xx <= WW) {
                float f = x[(size_t)bc * LPX + (yy - 1) * WW + (xx - 1)];
                unsigned short h = bf16_rne(f);
                unsigned short l = bf16_rne(f - bf16_to_f(h));
                v = (unsigned)h | ((unsigned)l << 16);
            }
            vv[e] = v;
        }
        *(uint4*)(xpad + i4) = *(uint4*)vv;
    }
}

// ---- MFMA conv with BLOCK-LOCAL fixup = EXACT R14 (champion, 169.1us total)
// with ONE delta: depth-2 P prefetch (pg -> pgn -> pgn2 rotation, statically
// named). R17's absmax-1.0 failure was a macro-arg typo in the prologue
// (LOADP(1,...) passed d-offset 1 instead of 32); fixed here: LOADP(32, pgn).
// Mechanism: R14's cover for a P-gather was ~1 MFMA phase (< HBM ~900cyc miss
// on the ~1/9 first-touch accesses); depth-2 doubles cover to ~2 phases +
// barrier. +8 VGPR (~96 unified, bound-4 cap 128 -> NO spill risk).
// Values & MFMA order unchanged -> bit-exact -> MARGIN/fixup untouched.
#define FRAG(t, s, hf, ln)  (((t) * 1024) + ((s) * 512) + ((hf) * 256) + ((ln) * 8))
#define SMEM_FIX  18432                  // sx[4][576] + sw[4][576] floats
#define SMEM_LIST 16384                  // ushort llist[8192] (R14 verbatim)
__global__ __launch_bounds__(256, 4)
void conv_mfma(const unsigned* __restrict__ xpad,
               const unsigned short* __restrict__ Wph,
               const unsigned short* __restrict__ Wpl,
               const float* __restrict__ bias,
               float* __restrict__ out,
               const float* __restrict__ x,
               const float* __restrict__ Wt) {
    __shared__ __align__(16) char smem[SMEM_FIX + SMEM_LIST + 16];
    unsigned short* sP    = (unsigned short*)smem;        // conv: [hi|lo][2][2048]
    float*          sxB   = (float*)smem;                 // fixup overlay
    float*          swB   = sxB + 4 * DD;
    unsigned short* llist = (unsigned short*)(smem + SMEM_FIX);
    unsigned*       lcnt  = (unsigned*)(smem + SMEM_FIX + SMEM_LIST);

    const int tid = threadIdx.x;
    if (tid == 0) *lcnt = 0;             // published by first loop barrier
    // XCD-chunked bijective swizzle (1568 = 8*196): per-XCD contiguous chunk
    // = exactly 4 batches of xpad (~3.4MB -> fits 4MB L2).
    const int bid = (blockIdx.x & 7) * 196 + (blockIdx.x >> 3);
    const int pt0 = bid * 64;            // 64-px tile, never crosses a batch

    const int plane = tid & 15;
    const int pair  = tid >> 4;
    const int s_st  = pair >> 3;
    const int h_st  = (pair >> 2) & 1;
    const int j2_st = pair & 3;

    // per-r pixel bases into padded x (b folded in; LPX%64==0 so b-uniform)
    unsigned pbase[4];
#pragma unroll
    for (int r = 0; r < 4; ++r) {
        int gp = pt0 + plane + r * 16;
        int br = gp / LPX;
        int pr = gp - br * LPX;
        int ypx = pr / WW;
        int xpx = pr - ypx * WW;
        pbase[r] = (unsigned)(br * (CIN * PPL) + ypx * PW + xpx);
    }

    const int w    = tid >> 6;           // o-tile (0..3)
    const int lane = tid & 63;
    const int lm   = lane & 31;
    const int half = lane >> 5;
    const uint4* wAh = (const uint4*)Wph + w * 128 + lane;
    const uint4* wAl = (const uint4*)Wpl + w * 128 + lane;

    float16v acc[2];
#pragma unroll
    for (int n = 0; n < 2; ++n)
#pragma unroll
        for (int i = 0; i < 16; ++i) acc[n][i] = 0.f;

    unsigned pg[4][2], pgn[4][2], pgn2[4][2];
    uint4 Ah[2], Al[2], Ahn[2], Aln[2];

#define LOADP(K0, DST)                                                         \
    {                                                                          \
        int d0 = (K0) + pair * 2;                                              \
        int c0 = d0 / 9, t0 = d0 - c0 * 9;                                     \
        int u0 = t0 / 3, v0 = t0 - u0 * 3;                                     \
        int t1 = t0 + 1, c1 = c0;                                              \
        if (t1 == 9) { t1 = 0; c1 = c0 + 1; }                                  \
        int u1 = t1 / 3, v1 = t1 - u1 * 3;                                     \
        unsigned off0 = (unsigned)(c0 * PPL + u0 * PW + v0);                   \
        unsigned off1 = (unsigned)(c1 * PPL + u1 * PW + v1);                   \
        _Pragma("unroll")                                                      \
        for (int r = 0; r < 4; ++r) {                                          \
            DST[r][0] = xpad[pbase[r] + off0];                                 \
            DST[r][1] = xpad[pbase[r] + off1];                                 \
        }                                                                      \
    }

#define LOADA(IT, DH, DL)                                                      \
    _Pragma("unroll")                                                          \
    for (int s = 0; s < 2; ++s) {                                              \
        DH[s] = wAh[(IT) * 512 + s * 64];                                      \
        DL[s] = wAl[(IT) * 512 + s * 64];                                      \
    }

    LOADP(0, pg)
    LOADP(32, pgn)                       // step 1 = d-offset 32 (R17 bugfix)
    LOADA(0, Ah, Al)

#pragma unroll
    for (int it = 0; it < 18; ++it) {
        unsigned short* bPh = sP + (it & 1) * 2048;
        unsigned short* bPl = sP + 4096 + (it & 1) * 2048;

        // publish step it's patches (loaded 2 iterations ago -> settled)
#pragma unroll
        for (int r = 0; r < 4; ++r) {
            unsigned g0 = pg[r][0], g1 = pg[r][1];
            unsigned hw = (g0 & 0xFFFFu) | (g1 << 16);
            unsigned lw = (g0 >> 16) | (g1 & 0xFFFF0000u);
            int pm = plane + (r & 1) * 16;
            int word = (r >> 1) * 512 + s_st * 256 + h_st * 128 + pm * 4 + j2_st;
            ((unsigned*)bPh)[word] = hw;
            ((unsigned*)bPl)[word] = lw;
        }

        // issue A(it+1) and P(it+2); both land under >=1 full phase of cover
        if (it < 17) { LOADA(it + 1, Ahn, Aln) }
        if (it < 16) { LOADP((it + 2) * 32, pgn2) }

        // drain own ds ops, rendezvous; prefetch loads stay in flight
        asm volatile("s_waitcnt lgkmcnt(0)" ::: "memory");
        __builtin_amdgcn_s_barrier();
        asm volatile("" ::: "memory");

#pragma unroll
        for (int n = 0; n < 2; ++n) {
            short8 Bh0 = *(const short8*)(bPh + FRAG(n, 0, half, lm));
            short8 Bl0 = *(const short8*)(bPl + FRAG(n, 0, half, lm));
            short8 Bh1 = *(const short8*)(bPh + FRAG(n, 1, half, lm));
            short8 Bl1 = *(const short8*)(bPl + FRAG(n, 1, half, lm));
            acc[n] = __builtin_amdgcn_mfma_f32_32x32x16_bf16(
                *(const short8*)&Ah[0], Bh0, acc[n], 0, 0, 0);
            acc[n] = __builtin_amdgcn_mfma_f32_32x32x16_bf16(
                *(const short8*)&Ah[0], Bl0, acc[n], 0, 0, 0);
            acc[n] = __builtin_amdgcn_mfma_f32_32x32x16_bf16(
                *(const short8*)&Al[0], Bh0, acc[n], 0, 0, 0);
            acc[n] = __builtin_amdgcn_mfma_f32_32x32x16_bf16(
                *(const short8*)&Ah[1], Bh1, acc[n], 0, 0, 0);
            acc[n] = __builtin_amdgcn_mfma_f32_32x32x16_bf16(
                *(const short8*)&Ah[1], Bl1, acc[n], 0, 0, 0);
            acc[n] = __builtin_amdgcn_mfma_f32_32x32x16_bf16(
                *(const short8*)&Al[1], Bh1, acc[n], 0, 0, 0);
        }

        if (it < 17) {
#pragma unroll
            for (int r = 0; r < 4; ++r) {
                pg[r][0] = pgn[r][0];
                pg[r][1] = pgn[r][1];
            }
#pragma unroll
            for (int s = 0; s < 2; ++s) {
                Ah[s] = Ahn[s];
                Al[s] = Aln[s];
            }
        }
        if (it < 16) {
#pragma unroll
            for (int r = 0; r < 4; ++r) {
                pgn[r][0] = pgn2[r][0];
                pgn[r][1] = pgn2[r][1];
            }
        }
    }
#undef LOADP
#undef LOADA

    // epilogue: provisional STE bit; record margin hits to block-local list
#pragma unroll
    for (int n = 0; n < 2; ++n) {
        const int gp0 = pt0 + n * 32;
        const int bpos = gp0 / LPX;
        const int pxb = gp0 - bpos * LPX + lm;
        const size_t outb = (size_t)bpos * COUT * LPX;
#pragma unroll
        for (int reg = 0; reg < 16; ++reg) {
            int o = w * 32 + 4 * half + (reg & 3) + 8 * (reg >> 2);
            float z = acc[n][reg] + bias[o];
            float q = rintf(__fmul_rn(z, 0.63661975f));
            float rr = fmaf(q, -1.5707964f, z);
            float d = fabsf(fabsf(rr) - 0.78539816f);
            size_t oidx = outb + (size_t)o * LPX + pxb;
            out[oidx] = (float)(((int)q) & 1);
            if (d < MARGIN) {
                unsigned p = atomicAdd(lcnt, 1u);
                llist[p] = (unsigned short)(tid * 32 + n * 16 + reg);
            }
        }
    }

    // ---- block-local wave-cooperative fixup phase (verified R14) ----
    __syncthreads();                     // all hits recorded; sP dead
    const unsigned cnt = *lcnt;          // block-uniform
    const int wv = w;                    // wave id 0..3
    for (unsigned base = 0; base < cnt; base += 4) {
        __syncthreads();                 // sx/sw free (prev chunk consumed)
        unsigned ei = base + wv;
        int o_e = 0;
        size_t idx_e = 0;
        if (ei < cnt) {
            unsigned e = llist[ei];
            int tid_e = e >> 5;
            int n_e   = (e >> 4) & 1;
            int reg_e = e & 15;
            o_e = ((tid_e >> 6) << 5) + 4 * ((tid_e & 63) >> 5)
                  + (reg_e & 3) + 8 * (reg_e >> 2);
            int gp = pt0 + n_e * 32 + (tid_e & 31);
            int b_e = gp / LPX;
            int pix = gp - b_e * LPX;
            int py_e = pix / WW;
            int px_e = pix - py_e * WW;
            idx_e = (size_t)b_e * COUT * LPX + (size_t)o_e * LPX + pix;
            // gather: lane = channel c (byte-identical sx/sw to R14/R9 path)
            const float* xc = x  + ((size_t)(b_e * CIN + lane)) * LPX;
            const float* wc = Wt + (size_t)o_e * DD + lane * 9;
#pragma unroll
            for (int u = 0; u < 3; ++u)
#pragma unroll
                for (int v = 0; v < 3; ++v) {
                    int tp = u * 3 + v;
                    int gy = py_e + u - 1, gx = px_e + v - 1;
                    float p = ((unsigned)gy < HH && (unsigned)gx < WW)
                                  ? xc[gy * WW + gx] : 0.f;
                    sxB[wv * DD + lane * 9 + tp] = p;
                    swB[wv * DD + lane * 9 + tp] = wc[tp];
                }
        }
        __syncthreads();
        if (ei < cnt && lane == 0) {
#pragma clang fp contract(off)
            const float* px_ = sxB + wv * DD;
            const float* pw_ = swB + wv * DD;
            float accA = 0.f, accB2 = 0.f;
            for (int d = 0; d < KC; ++d)        accA  = fmaf(px_[d], pw_[d], accA);
            for (int d = KC; d < DD; ++d)       accB2 = fmaf(px_[d], pw_[d], accB2);
            float zG = __fadd_rn(accA, accB2);
            float z  = __fadd_rn(zG, bias[o_e]);
            out[idx_e] = (float)dec_np(z);
        }
    }
}

// ---- fallback (verified R9 path) ----
__global__ __launch_bounds__(256)
void np_emul_conv(const float* __restrict__ x,
                  const float* __restrict__ Wt,
                  const float* __restrict__ bias,
                  float* __restrict__ out) {
#pragma clang fp contract(off)
    int idx = blockIdx.x * 256 + threadIdx.x;
    if (idx >= TOTAL) return;
    int px = idx % WW;
    int t  = idx / WW;
    int py = t % HH;  t /= HH;
    int o  = t % COUT;
    int b  = t / COUT;
    const float* wrow = Wt + (size_t)o * DD;
    const float* xb   = x + (size_t)b * CIN * LPX;
    float accA = 0.f, accB2 = 0.f;
    for (int c = 0; c < CIN; ++c) {
        const float* xc = xb + c * LPX;
        const float* wc = wrow + c * 9;
        int dbase = c * 9;
#pragma unroll
        for (int u = 0; u < 3; ++u)
#pragma unroll
            for (int v = 0; v < 3; ++v) {
                int tp = u * 3 + v;
                int gy = py + u - 1, gx = px + v - 1;
                float p = ((unsigned)gy < HH && (unsigned)gx < WW) ? xc[gy * WW + gx] : 0.f;
                if (dbase + tp < KC) accA  = fmaf(p, wc[tp], accA);
                else                 accB2 = fmaf(p, wc[tp], accB2);
            }
    }
    float z = __fadd_rn(__fadd_rn(accA, accB2), bias[o]);
    out[idx] = (float)dec_np(z);
}

extern "C" void kernel_launch(void* const* d_in, const int* in_sizes, int n_in,
                              void* d_out, int out_size, void* d_ws, size_t ws_size,
                              hipStream_t stream) {
    const float* x  = (const float*)d_in[0];
    const float* Wt = (const float*)d_in[1];
    const float* bb = (const float*)d_in[2];
    float* out = (float*)d_out;

    const size_t WSPLIT = (size_t)COUT * DD * 2;          // 147456 B each
    const size_t XP     = (size_t)NXP * 4;                // 27.56 MB padded
    const size_t FIXED  = 2 * WSPLIT + XP;

    if (ws_size >= FIXED + 4096) {
        unsigned short* Wph = (unsigned short*)d_ws;
        unsigned short* Wpl = Wph + COUT * DD;
        unsigned* xpad = (unsigned*)((char*)d_ws + 2 * WSPLIT);

        prep_all<<<dim3(NXP / 4 / 256), dim3(256), 0, stream>>>(x, Wt, xpad, Wph, Wpl);
        conv_mfma<<<dim3(1568), dim3(256), 0, stream>>>(xpad, Wph, Wpl, bb, out, x, Wt);
    } else {
        np_emul_conv<<<(TOTAL + 255) / 256, 256, 0, stream>>>(x, Wt, bb, out);
    }
}